// Round 15
// baseline (130.406 us; speedup 1.0000x reference)
//
#include <hip/hip_runtime.h>
#include <hip/hip_bf16.h>

#define BB 256
#define NN 64
#define NNODES 16384   // BB*NN
#define ND 11
#define TGT 12

// k_prep role bases
#define NB_DEG   64
#define NB_MEDEG 4096
#define NB_CVTR  96
#define NB_CVTW  352
#define NB_MH0   256
#define NB_TOTAL (NB_DEG + NB_MEDEG + NB_CVTR + NB_CVTW + NB_MH0)

typedef __attribute__((ext_vector_type(8))) short s16x8;
typedef __attribute__((ext_vector_type(4))) float f32x4;

__device__ __forceinline__ float sig1(float v) { return 1.f / (1.f + __expf(-v)); }
__device__ __forceinline__ float bf2f(unsigned short u) {
    union { unsigned int i; float f; } v; v.i = ((unsigned int)u) << 16; return v.f;
}
__device__ __forceinline__ unsigned short f2bf(float f) {
    __hip_bfloat16 b = __float2bfloat16(f);   // RNE
    return *reinterpret_cast<unsigned short*>(&b);
}

// ================= D1: mega-prep =================
// roles: [deg | me_deg(SPARSE) | cvt_R | cvt_W(0+1) | mh0+cvt_h]
__global__ __launch_bounds__(256) void k_prep(
        const float* __restrict__ g, const float* __restrict__ e,
        const float* __restrict__ h_in, const float* __restrict__ R,
        const float* __restrict__ Wu0, const float* __restrict__ Wu1,
        unsigned short* __restrict__ Mb, unsigned short* __restrict__ hb0,
        unsigned short* __restrict__ Rtf, unsigned short* __restrict__ Wtf0,
        unsigned short* __restrict__ Wtf1, int* __restrict__ degidx,
        int* __restrict__ rowmap, int* __restrict__ cnt,
        unsigned short* __restrict__ hb1, unsigned short* __restrict__ hb2) {
    __shared__ __align__(16) unsigned char smem[32768];
    int bid = blockIdx.x;
    const int tid = threadIdx.x;
    const int lane = tid & 63, wv = tid >> 6;
    const int gq = lane >> 4, c16 = lane & 15;

    if (bid < NB_DEG) {
        // ---- deg: degree + bucket rank (hierarchical), rowmap scatter, zero invalid rows ----
        int* hist = reinterpret_cast<int*>(smem);
        int* baseg = hist + ND;
        if (tid < ND) hist[tid] = 0;
        __syncthreads();
        const int node = bid * 256 + tid;
        const float4* gr = reinterpret_cast<const float4*>(g + (size_t)node * 64);
        float s = 0.f;
        #pragma unroll
        for (int j = 0; j < 16; ++j) { float4 v = gr[j]; s += v.x + v.y + v.z + v.w; }
        const int di = (int)(s + 0.5f);
        const bool valid = di < ND;
        int pl = 0;
        if (valid) pl = atomicAdd(&hist[di], 1);
        __syncthreads();
        if (tid < ND) baseg[tid] = hist[tid] ? atomicAdd(&cnt[tid], hist[tid]) : 0;
        __syncthreads();
        degidx[node] = valid ? di : -1;
        if (valid) {
            rowmap[di * NNODES + baseg[di] + pl] = node;
        } else {
            uint4 z = make_uint4(0, 0, 0, 0);
            uint4* p1 = reinterpret_cast<uint4*>(hb1 + (size_t)node * 256);
            uint4* p2 = reinterpret_cast<uint4*>(hb2 + (size_t)node * 256);
            #pragma unroll
            for (int k = 0; k < 32; ++k) { p1[k] = z; p2[k] = z; }
        }
        return;
    }
    bid -= NB_DEG;

    if (bid < NB_MEDEG) {
        // ---- me_deg SPARSE: m_e = sum of e-rows over set neighbors only (~5/64) ----
        const int node = bid * 4 + wv;
        const float gv = g[(size_t)node * 64 + lane];
        unsigned long long mask = __ballot(gv != 0.f);
        if (__popcll(mask) > 10) return;   // invalid: m_e never consumed
        const float* eb = e + (size_t)node * 4096;
        float acc = 0.f;
        while (mask) {
            int w = __builtin_ctzll(mask); mask &= mask - 1;
            acc += eb[w * 64 + lane];      // 256 B coalesced per neighbor
        }
        Mb[(size_t)node * 320 + 256 + lane] = f2bf(acc);
        return;
    }
    bid -= NB_MEDEG;

    if (bid < NB_CVTR) {
        // ---- cvt_R -> fragment order ----
        const int l = bid >> 5, cb = bid & 31;
        const float* Rl = R + (size_t)l * 256 * 512;
        unsigned short* outB = Rtf + ((size_t)l * 32 + cb) * 8 * 512;
        const int col = cb * 16 + c16;
        #pragma unroll
        for (int it = 0; it < 2; ++it) {
            int ks = wv + it * 4;
            unsigned short tmp[8];
            #pragma unroll
            for (int j = 0; j < 8; ++j)
                tmp[j] = f2bf(Rl[(size_t)(ks * 32 + gq * 8 + j) * 512 + col]);
            *reinterpret_cast<uint4*>(&outB[(size_t)ks * 512 + lane * 8]) =
                *reinterpret_cast<const uint4*>(tmp);
        }
        return;
    }
    bid -= NB_CVTR;

    if (bid < NB_CVTW) {
        // ---- cvt_W -> fragment order ----
        const int wsel = bid / 176, rem = bid % 176;
        const int d = rem >> 4, cb = rem & 15;
        const float* Wd = (wsel ? Wu1 : Wu0) + (size_t)d * 320 * 256;
        unsigned short* outB = (wsel ? Wtf1 : Wtf0) + ((size_t)d * 16 + cb) * 10 * 512;
        const int col = cb * 16 + c16;
        #pragma unroll
        for (int it = 0; it < 3; ++it) {
            int ks = wv + it * 4;
            if (ks < 10) {
                unsigned short tmp[8];
                #pragma unroll
                for (int j = 0; j < 8; ++j)
                    tmp[j] = f2bf(Wd[(size_t)(ks * 32 + gq * 8 + j) * 256 + col]);
                *reinterpret_cast<uint4*>(&outB[(size_t)ks * 512 + lane * 8]) =
                    *reinterpret_cast<const uint4*>(tmp);
            }
        }
        return;
    }
    bid -= NB_CVTW;

    // ---- mh0 + cvt_h: stage h_in as bf16 (write hb0 on the way), sparse m_h -> Mb ----
    {
        unsigned short* hs = reinterpret_cast<unsigned short*>(smem);  // [64][256] bf16
        const int b = bid;
        const float4* hin4 = reinterpret_cast<const float4*>(h_in) + (size_t)b * 4096;
        ushort4* hb0b = reinterpret_cast<ushort4*>(hb0 + (size_t)b * NN * 256);
        #pragma unroll
        for (int j = 0; j < 16; ++j) {
            int i = j * 256 + tid;
            float4 v = hin4[i];
            ushort4 u = make_ushort4(f2bf(v.x), f2bf(v.y), f2bf(v.z), f2bf(v.w));
            *reinterpret_cast<ushort4*>(&hs[i * 4]) = u;
            hb0b[i] = u;   // cvt_h fused: one h_in pass
        }
        __syncthreads();
        for (int s = 0; s < 16; ++s) {
            const int v = wv * 16 + s;
            float gval = g[((size_t)b * 64 + v) * 64 + lane];
            unsigned long long mask = __ballot(gval != 0.f);
            if (__popcll(mask) > 10) continue;
            float4 acc = make_float4(0.f, 0.f, 0.f, 0.f);
            while (mask) {
                int w = __builtin_ctzll(mask); mask &= mask - 1;
                ushort4 hv = *reinterpret_cast<const ushort4*>(&hs[w * 256 + lane * 4]);
                acc.x += bf2f(hv.x); acc.y += bf2f(hv.y);
                acc.z += bf2f(hv.z); acc.w += bf2f(hv.w);
            }
            ushort4 u = make_ushort4(f2bf(acc.x), f2bf(acc.y), f2bf(acc.z), f2bf(acc.w));
            *reinterpret_cast<ushort4*>(&Mb[((size_t)b * 64 + v) * 320 + lane * 4]) = u;
        }
    }
}

// ================= D2/D4: grouped update; single-degree tiles, rowmap gather =================
// As/Ct alias one 40 KB LDS buffer -> 4 blocks/CU.
__global__ __launch_bounds__(256) void k_update(
        const unsigned short* __restrict__ Mb,
        const unsigned short* __restrict__ Wtf,
        const int* __restrict__ rowmap,
        const int* __restrict__ cnt,
        unsigned short* __restrict__ hout) {
    __shared__ __align__(16) unsigned short AsCt[64 * 320];   // 40 KB (As then Ct)
    __shared__ int nmap[64];
    __shared__ int scnt[ND];
    const int tid = threadIdx.x;
    if (tid < ND) scnt[tid] = cnt[tid];   // one coalesced load, not 11 serial
    __syncthreads();
    int rem = blockIdx.x, d = 0;
    for (; d < ND; ++d) { int td = (scnt[d] + 63) >> 6; if (rem < td) break; rem -= td; }
    if (d >= ND) return;
    const int cd = scnt[d];
    const int base = rem * 64;
    if (tid < 64) {
        int s = base + tid;
        nmap[tid] = (s < cd) ? rowmap[d * NNODES + s] : -1;
    }
    __syncthreads();
    const int grow = tid >> 2, gseg = tid & 3;
    {   // gather A rows with XOR swizzle on 16B granules: c ^= row&7
        int node = nmap[grow];
        if (node < 0) node = rowmap[d * NNODES];
        const char* src = reinterpret_cast<const char*>(Mb + (size_t)node * 320);
        char* dstA = reinterpret_cast<char*>(AsCt) + grow * 640;
        #pragma unroll
        for (int j = 0; j < 10; ++j) {
            int c = gseg + 4 * j;   // 0..39
            uint4 v = *reinterpret_cast<const uint4*>(src + c * 16);
            *reinterpret_cast<uint4*>(dstA + ((c ^ (grow & 7)) * 16)) = v;
        }
    }
    __syncthreads();
    const int w = tid >> 6, lane = tid & 63, gq = lane >> 4, c16 = lane & 15;
    const int swz = (c16 & 7) << 4;
    f32x4 acc[4][4];
    #pragma unroll
    for (int rt = 0; rt < 4; ++rt)
        #pragma unroll
        for (int ct = 0; ct < 4; ++ct) acc[rt][ct] = (f32x4){0.f, 0.f, 0.f, 0.f};
    #pragma unroll
    for (int ks = 0; ks < 10; ++ks) {
        s16x8 af[4], bf[4];
        #pragma unroll
        for (int rt = 0; rt < 4; ++rt)
            af[rt] = *reinterpret_cast<const s16x8*>(
                reinterpret_cast<const char*>(AsCt) + (rt * 16 + c16) * 640 +
                ((ks * 64 + gq * 16) ^ swz));
        #pragma unroll
        for (int ct = 0; ct < 4; ++ct) {
            int cb = w * 4 + ct;
            bf[ct] = *reinterpret_cast<const s16x8*>(
                &Wtf[((((size_t)d * 16 + cb) * 10 + ks) * 64 + lane) * 8]);
        }
        #pragma unroll
        for (int rt = 0; rt < 4; ++rt)
            #pragma unroll
            for (int ct = 0; ct < 4; ++ct)
                acc[rt][ct] = __builtin_amdgcn_mfma_f32_16x16x32_bf16(af[rt], bf[ct], acc[rt][ct], 0, 0, 0);
    }
    __syncthreads();   // all As reads done; AsCt becomes Ct
    #pragma unroll
    for (int rt = 0; rt < 4; ++rt)
        #pragma unroll
        for (int jj = 0; jj < 4; ++jj) {
            int row = rt * 16 + gq * 4 + jj;
            #pragma unroll
            for (int ct = 0; ct < 4; ++ct)
                AsCt[row * 256 + w * 64 + ct * 16 + c16] = f2bf(sig1(acc[rt][ct][jj]));
        }
    __syncthreads();
    {   // scatter rows to node order (512 B contiguous per row)
        const int node = nmap[grow];
        if (node >= 0) {
            const uint4* srcC = reinterpret_cast<const uint4*>(&AsCt[grow * 256]);
            uint4* dst = reinterpret_cast<uint4*>(hout + (size_t)node * 256);
            #pragma unroll
            for (int j = 0; j < 8; ++j) dst[gseg * 8 + j] = srcC[gseg * 8 + j];
        }
    }
}

// ================= D3: sparse m_h from bf16 h -> Mb cols 0..255 =================
__global__ __launch_bounds__(256) void k_mh_sparse(const float* __restrict__ g,
                                                   const unsigned short* __restrict__ hb,
                                                   unsigned short* __restrict__ Mb) {
    __shared__ __align__(16) unsigned short hs[NN * 256];   // 32 KB
    const int b = blockIdx.x;
    const int tid = threadIdx.x;
    {
        const uint4* src = reinterpret_cast<const uint4*>(hb) + (size_t)b * 2048;
        uint4* dst = reinterpret_cast<uint4*>(hs);
        #pragma unroll
        for (int j = 0; j < 8; ++j) dst[j * 256 + tid] = src[j * 256 + tid];
    }
    __syncthreads();
    const int wv = tid >> 6, lane = tid & 63;
    for (int s = 0; s < 16; ++s) {
        const int v = wv * 16 + s;
        float gval = g[((size_t)b * 64 + v) * 64 + lane];
        unsigned long long mask = __ballot(gval != 0.f);
        if (__popcll(mask) > 10) continue;
        float4 acc = make_float4(0.f, 0.f, 0.f, 0.f);
        while (mask) {
            int w = __builtin_ctzll(mask); mask &= mask - 1;
            ushort4 hv = *reinterpret_cast<const ushort4*>(&hs[w * 256 + lane * 4]);
            acc.x += bf2f(hv.x); acc.y += bf2f(hv.y);
            acc.z += bf2f(hv.z); acc.w += bf2f(hv.w);
        }
        ushort4 u = make_ushort4(f2bf(acc.x), f2bf(acc.y), f2bf(acc.z), f2bf(acc.w));
        *reinterpret_cast<ushort4*>(&Mb[((size_t)b * 64 + v) * 320 + lane * 4]) = u;
    }
}

// ================= D5: readout (3 layers, LDS-staged A + frag B) + MLP =================
__global__ __launch_bounds__(256) void k_readout_mlp(
        const unsigned short* __restrict__ hb0,
        const unsigned short* __restrict__ hb1,
        const unsigned short* __restrict__ hb2,
        const unsigned short* __restrict__ Rtf,
        const int* __restrict__ degidx,
        const float* __restrict__ fc0w, const float* __restrict__ fc0b,
        const float* __restrict__ fc1w, const float* __restrict__ fc1b,
        const float* __restrict__ fc2w, const float* __restrict__ fc2b,
        const float* __restrict__ fc3w, const float* __restrict__ fc3b,
        float* __restrict__ out) {
    const int b = blockIdx.x;
    const int tid = threadIdx.x;
    const int w = tid >> 6, lane = tid & 63, gq = lane >> 4, c16 = lane & 15;
    __shared__ __align__(16) unsigned short Ah[64 * 256];   // 32 KB swizzled
    __shared__ float x0[512];
    __shared__ float red2[4][64];
    __shared__ __align__(16) float red3[64];
    __shared__ float flags[64];
    __shared__ float part[256];
    __shared__ float x1[128], x2[256], x3[128];
    if (tid < 64) flags[tid] = (degidx[b * 64 + tid] >= 0) ? 1.f : 0.f;
    x0[tid] = 0.f; x0[tid + 256] = 0.f;
    const int swz = (c16 & 7) << 4;

    for (int layer = 0; layer < 3; ++layer) {
        const unsigned short* hb = (layer == 0) ? hb0 : ((layer == 1) ? hb1 : hb2);
        {   // stage A tile, XOR-swizzled
            const char* src = reinterpret_cast<const char*>(hb + (size_t)b * 64 * 256);
            #pragma unroll
            for (int j = 0; j < 8; ++j) {
                int l = j * 4096 + tid * 16;
                int row = l >> 9;
                int wb = l & 511;
                uint4 v = *reinterpret_cast<const uint4*>(src + l);
                *reinterpret_cast<uint4*>(
                    reinterpret_cast<char*>(Ah) + row * 512 + (wb ^ ((row & 7) << 4))) = v;
            }
        }
        __syncthreads();
        f32x4 acc[4][8];
        #pragma unroll
        for (int rt = 0; rt < 4; ++rt)
            #pragma unroll
            for (int ct = 0; ct < 8; ++ct) acc[rt][ct] = (f32x4){0.f, 0.f, 0.f, 0.f};
        #pragma unroll
        for (int ks = 0; ks < 8; ++ks) {
            s16x8 af[4], bf[8];
            #pragma unroll
            for (int rt = 0; rt < 4; ++rt)
                af[rt] = *reinterpret_cast<const s16x8*>(
                    reinterpret_cast<const char*>(Ah) + (rt * 16 + c16) * 512 +
                    ((ks * 64 + gq * 16) ^ swz));
            #pragma unroll
            for (int ct = 0; ct < 8; ++ct)
                bf[ct] = *reinterpret_cast<const s16x8*>(
                    &Rtf[((((size_t)layer * 32 + w * 8 + ct) * 8 + ks) * 64 + lane) * 8]);
            #pragma unroll
            for (int rt = 0; rt < 4; ++rt)
                #pragma unroll
                for (int ct = 0; ct < 8; ++ct)
                    acc[rt][ct] = __builtin_amdgcn_mfma_f32_16x16x32_bf16(af[rt], bf[ct], acc[rt][ct], 0, 0, 0);
        }
        // exp in place; per-row sums over this wave's 128 cols
        float rs[4][4];
        #pragma unroll
        for (int rt = 0; rt < 4; ++rt) {
            #pragma unroll
            for (int j = 0; j < 4; ++j) rs[rt][j] = 0.f;
            #pragma unroll
            for (int ct = 0; ct < 8; ++ct) {
                #pragma unroll
                for (int j = 0; j < 4; ++j) {
                    float p = __expf(acc[rt][ct][j]);
                    acc[rt][ct][j] = p;
                    rs[rt][j] += p;
                }
            }
        }
        #pragma unroll
        for (int rt = 0; rt < 4; ++rt)
            #pragma unroll
            for (int j = 0; j < 4; ++j) {
                float s = rs[rt][j];
                #pragma unroll
                for (int m = 1; m <= 8; m <<= 1) s += __shfl_xor(s, m);
                rs[rt][j] = s;
            }
        if (c16 == 0) {
            #pragma unroll
            for (int rt = 0; rt < 4; ++rt)
                #pragma unroll
                for (int j = 0; j < 4; ++j)
                    red2[w][rt * 16 + gq * 4 + j] = rs[rt][j];
        }
        __syncthreads();
        if (tid < 64) {
            float s = red2[0][tid] + red2[1][tid] + red2[2][tid] + red2[3][tid];
            red3[tid] = ((layer == 0) ? 1.f : flags[tid]) / s;
        }
        __syncthreads();
        f32x4 iv[4];
        #pragma unroll
        for (int rt = 0; rt < 4; ++rt)
            iv[rt] = *reinterpret_cast<const f32x4*>(&red3[rt * 16 + gq * 4]);
        #pragma unroll
        for (int ct = 0; ct < 8; ++ct) {
            f32x4 t = (f32x4){0.f, 0.f, 0.f, 0.f};
            #pragma unroll
            for (int rt = 0; rt < 4; ++rt) t += acc[rt][ct] * iv[rt];
            float v = t[0] + t[1] + t[2] + t[3];
            v += __shfl_xor(v, 16);
            v += __shfl_xor(v, 32);
            if (lane < 16) x0[w * 128 + ct * 16 + lane] += v;
        }
        __syncthreads();
    }
    // ---- MLP on x0[512] ----
    {
        const int o = tid & 127, half = tid >> 7;
        float a = 0.f;
        const int i0 = half * 256;
        for (int i = 0; i < 256; ++i) a = fmaf(x0[i0 + i], fc0w[(size_t)(i0 + i) * 128 + o], a);
        part[tid] = a;
    }
    __syncthreads();
    if (tid < 128) x1[tid] = fmaxf(fc0b[tid] + part[tid] + part[tid + 128], 0.f);
    __syncthreads();
    {
        float a = fc1b[tid];
        for (int i = 0; i < 128; ++i) a = fmaf(x1[i], fc1w[(size_t)i * 256 + tid], a);
        x2[tid] = fmaxf(a, 0.f);
    }
    __syncthreads();
    {
        const int o = tid & 127, half = tid >> 7;
        float a = 0.f;
        const int i0 = half * 128;
        for (int i = 0; i < 128; ++i) a = fmaf(x2[i0 + i], fc2w[(size_t)(i0 + i) * 128 + o], a);
        part[tid] = a;
    }
    __syncthreads();
    if (tid < 128) x3[tid] = fmaxf(fc2b[tid] + part[tid] + part[tid + 128], 0.f);
    __syncthreads();
    if (tid < TGT) {
        float a = fc3b[tid];
        for (int i = 0; i < 128; ++i) a = fmaf(x3[i], fc3w[(size_t)i * TGT + tid], a);
        out[(size_t)b * TGT + tid] = a;
    }
}

extern "C" void kernel_launch(void* const* d_in, const int* in_sizes, int n_in,
                              void* d_out, int out_size, void* d_ws, size_t ws_size,
                              hipStream_t stream) {
    (void)in_sizes; (void)n_in; (void)out_size; (void)ws_size;
    const float* g    = (const float*)d_in[0];
    const float* h_in = (const float*)d_in[1];
    const float* e    = (const float*)d_in[2];
    const float* Wu0  = (const float*)d_in[3];
    const float* Wu1  = (const float*)d_in[4];
    const float* R    = (const float*)d_in[5];
    const float* fc0w = (const float*)d_in[6];
    const float* fc0b = (const float*)d_in[7];
    const float* fc1w = (const float*)d_in[8];
    const float* fc1b = (const float*)d_in[9];
    const float* fc2w = (const float*)d_in[10];
    const float* fc2b = (const float*)d_in[11];
    const float* fc3w = (const float*)d_in[12];
    const float* fc3b = (const float*)d_in[13];
    float* out = (float*)d_out;

    char* p = (char*)d_ws;
    unsigned short* Mb   = (unsigned short*)p; p += (size_t)NNODES * 320 * 2;       // 10 MB
    unsigned short* hb0  = (unsigned short*)p; p += (size_t)NNODES * 256 * 2;       // 8 MB
    unsigned short* hb1  = (unsigned short*)p; p += (size_t)NNODES * 256 * 2;       // 8 MB
    unsigned short* hb2  = (unsigned short*)p; p += (size_t)NNODES * 256 * 2;       // 8 MB
    unsigned short* Rtf  = (unsigned short*)p; p += (size_t)3 * 32 * 8 * 512 * 2;   // 0.75 MB
    unsigned short* Wtf0 = (unsigned short*)p; p += (size_t)ND * 16 * 10 * 512 * 2; // 1.76 MB
    unsigned short* Wtf1 = (unsigned short*)p; p += (size_t)ND * 16 * 10 * 512 * 2; // 1.76 MB
    int* degidx = (int*)p;                     p += (size_t)NNODES * 4;             // 64 KB
    int* rowmap = (int*)p;                     p += (size_t)ND * NNODES * 4;        // 704 KB
    int* cnt    = (int*)p;                     p += 1024;

    hipMemsetAsync(cnt, 0, ND * sizeof(int), stream);
    k_prep<<<NB_TOTAL, 256, 0, stream>>>(g, e, h_in, R, Wu0, Wu1,
                                         Mb, hb0, Rtf, Wtf0, Wtf1,
                                         degidx, rowmap, cnt, hb1, hb2);
    k_update<<<NNODES / 64 + ND, 256, 0, stream>>>(Mb, Wtf0, rowmap, cnt, hb1);
    k_mh_sparse<<<BB, 256, 0, stream>>>(g, hb1, Mb);
    k_update<<<NNODES / 64 + ND, 256, 0, stream>>>(Mb, Wtf1, rowmap, cnt, hb2);
    k_readout_mlp<<<BB, 256, 0, stream>>>(hb0, hb1, hb2, Rtf, degidx,
                                          fc0w, fc0b, fc1w, fc1b, fc2w, fc2b, fc3w, fc3b, out);
}

// Round 16
// 127.209 us; speedup vs baseline: 1.0251x; 1.0251x over previous
//
#include <hip/hip_runtime.h>
#include <hip/hip_bf16.h>

#define BB 256
#define NN 64
#define NNODES 16384   // BB*NN
#define ND 11
#define TGT 12

// k_prep_light role bases (no-LDS roles)
#define NB_DEG   64
#define NB_MEDEG 4096
#define NB_CVTR  96
#define NB_CVTW  352
#define NB_LIGHT (NB_DEG + NB_MEDEG + NB_CVTR + NB_CVTW)

typedef __attribute__((ext_vector_type(8))) short s16x8;
typedef __attribute__((ext_vector_type(4))) float f32x4;

__device__ __forceinline__ float sig1(float v) { return 1.f / (1.f + __expf(-v)); }
__device__ __forceinline__ float bf2f(unsigned short u) {
    union { unsigned int i; float f; } v; v.i = ((unsigned int)u) << 16; return v.f;
}
__device__ __forceinline__ unsigned short f2bf(float f) {
    __hip_bfloat16 b = __float2bfloat16(f);   // RNE
    return *reinterpret_cast<unsigned short*>(&b);
}

// ================= D1a: light prep (88 B LDS -> 8 blocks/CU) =================
// roles: [deg | me_deg(SPARSE) | cvt_R | cvt_W(0+1)]
__global__ __launch_bounds__(256) void k_prep_light(
        const float* __restrict__ g, const float* __restrict__ e,
        const float* __restrict__ R,
        const float* __restrict__ Wu0, const float* __restrict__ Wu1,
        unsigned short* __restrict__ Mb,
        unsigned short* __restrict__ Rtf, unsigned short* __restrict__ Wtf0,
        unsigned short* __restrict__ Wtf1, int* __restrict__ degidx,
        int* __restrict__ rowmap, int* __restrict__ cnt,
        unsigned short* __restrict__ hb1, unsigned short* __restrict__ hb2) {
    __shared__ int hist[ND];
    __shared__ int baseg[ND];
    int bid = blockIdx.x;
    const int tid = threadIdx.x;
    const int lane = tid & 63, wv = tid >> 6;
    const int gq = lane >> 4, c16 = lane & 15;

    if (bid < NB_DEG) {
        // ---- deg: degree + bucket rank (hierarchical), rowmap scatter, zero invalid rows ----
        if (tid < ND) hist[tid] = 0;
        __syncthreads();
        const int node = bid * 256 + tid;
        const float4* gr = reinterpret_cast<const float4*>(g + (size_t)node * 64);
        float s = 0.f;
        #pragma unroll
        for (int j = 0; j < 16; ++j) { float4 v = gr[j]; s += v.x + v.y + v.z + v.w; }
        const int di = (int)(s + 0.5f);
        const bool valid = di < ND;
        int pl = 0;
        if (valid) pl = atomicAdd(&hist[di], 1);
        __syncthreads();
        if (tid < ND) baseg[tid] = hist[tid] ? atomicAdd(&cnt[tid], hist[tid]) : 0;
        __syncthreads();
        degidx[node] = valid ? di : -1;
        if (valid) {
            rowmap[di * NNODES + baseg[di] + pl] = node;
        } else {
            uint4 z = make_uint4(0, 0, 0, 0);
            uint4* p1 = reinterpret_cast<uint4*>(hb1 + (size_t)node * 256);
            uint4* p2 = reinterpret_cast<uint4*>(hb2 + (size_t)node * 256);
            #pragma unroll
            for (int k = 0; k < 32; ++k) { p1[k] = z; p2[k] = z; }
        }
        return;
    }
    bid -= NB_DEG;

    if (bid < NB_MEDEG) {
        // ---- me_deg SPARSE: m_e = sum of e-rows over set neighbors only (~5/64) ----
        const int node = bid * 4 + wv;
        const float gv = g[(size_t)node * 64 + lane];
        unsigned long long mask = __ballot(gv != 0.f);
        if (__popcll(mask) > 10) return;   // invalid: m_e never consumed
        const float* eb = e + (size_t)node * 4096;
        float acc = 0.f;
        while (mask) {
            int w = __builtin_ctzll(mask); mask &= mask - 1;
            acc += eb[w * 64 + lane];      // 256 B coalesced per neighbor
        }
        Mb[(size_t)node * 320 + 256 + lane] = f2bf(acc);
        return;
    }
    bid -= NB_MEDEG;

    if (bid < NB_CVTR) {
        // ---- cvt_R -> fragment order ----
        const int l = bid >> 5, cb = bid & 31;
        const float* Rl = R + (size_t)l * 256 * 512;
        unsigned short* outB = Rtf + ((size_t)l * 32 + cb) * 8 * 512;
        const int col = cb * 16 + c16;
        #pragma unroll
        for (int it = 0; it < 2; ++it) {
            int ks = wv + it * 4;
            unsigned short tmp[8];
            #pragma unroll
            for (int j = 0; j < 8; ++j)
                tmp[j] = f2bf(Rl[(size_t)(ks * 32 + gq * 8 + j) * 512 + col]);
            *reinterpret_cast<uint4*>(&outB[(size_t)ks * 512 + lane * 8]) =
                *reinterpret_cast<const uint4*>(tmp);
        }
        return;
    }
    bid -= NB_CVTR;

    {   // ---- cvt_W -> fragment order ----
        const int wsel = bid / 176, rem = bid % 176;
        const int d = rem >> 4, cb = rem & 15;
        const float* Wd = (wsel ? Wu1 : Wu0) + (size_t)d * 320 * 256;
        unsigned short* outB = (wsel ? Wtf1 : Wtf0) + ((size_t)d * 16 + cb) * 10 * 512;
        const int col = cb * 16 + c16;
        #pragma unroll
        for (int it = 0; it < 3; ++it) {
            int ks = wv + it * 4;
            if (ks < 10) {
                unsigned short tmp[8];
                #pragma unroll
                for (int j = 0; j < 8; ++j)
                    tmp[j] = f2bf(Wd[(size_t)(ks * 32 + gq * 8 + j) * 256 + col]);
                *reinterpret_cast<uint4*>(&outB[(size_t)ks * 512 + lane * 8]) =
                    *reinterpret_cast<const uint4*>(tmp);
            }
        }
    }
}

// ================= D1b: mh0 + cvt_h (32 KB LDS, 256 blocks) =================
__global__ __launch_bounds__(256) void k_prep_mh(
        const float* __restrict__ g, const float* __restrict__ h_in,
        unsigned short* __restrict__ Mb, unsigned short* __restrict__ hb0) {
    __shared__ __align__(16) unsigned short hs[NN * 256];   // 32 KB
    const int b = blockIdx.x;
    const int tid = threadIdx.x;
    const int lane = tid & 63, wv = tid >> 6;
    const float4* hin4 = reinterpret_cast<const float4*>(h_in) + (size_t)b * 4096;
    ushort4* hb0b = reinterpret_cast<ushort4*>(hb0 + (size_t)b * NN * 256);
    #pragma unroll
    for (int j = 0; j < 16; ++j) {
        int i = j * 256 + tid;
        float4 v = hin4[i];
        ushort4 u = make_ushort4(f2bf(v.x), f2bf(v.y), f2bf(v.z), f2bf(v.w));
        *reinterpret_cast<ushort4*>(&hs[i * 4]) = u;
        hb0b[i] = u;   // cvt_h fused: one h_in pass
    }
    __syncthreads();
    for (int s = 0; s < 16; ++s) {
        const int v = wv * 16 + s;
        float gval = g[((size_t)b * 64 + v) * 64 + lane];
        unsigned long long mask = __ballot(gval != 0.f);
        if (__popcll(mask) > 10) continue;
        float4 acc = make_float4(0.f, 0.f, 0.f, 0.f);
        while (mask) {
            int w = __builtin_ctzll(mask); mask &= mask - 1;
            ushort4 hv = *reinterpret_cast<const ushort4*>(&hs[w * 256 + lane * 4]);
            acc.x += bf2f(hv.x); acc.y += bf2f(hv.y);
            acc.z += bf2f(hv.z); acc.w += bf2f(hv.w);
        }
        ushort4 u = make_ushort4(f2bf(acc.x), f2bf(acc.y), f2bf(acc.z), f2bf(acc.w));
        *reinterpret_cast<ushort4*>(&Mb[((size_t)b * 64 + v) * 320 + lane * 4]) = u;
    }
}

// ================= D3/D5: grouped update; single-degree tiles, rowmap gather =================
__global__ __launch_bounds__(256) void k_update(
        const unsigned short* __restrict__ Mb,
        const unsigned short* __restrict__ Wtf,
        const int* __restrict__ rowmap,
        const int* __restrict__ cnt,
        unsigned short* __restrict__ hout) {
    __shared__ __align__(16) unsigned short AsCt[64 * 320];   // 40 KB (As then Ct)
    __shared__ int nmap[64];
    __shared__ int scnt[ND];
    const int tid = threadIdx.x;
    if (tid < ND) scnt[tid] = cnt[tid];
    __syncthreads();
    int rem = blockIdx.x, d = 0;
    for (; d < ND; ++d) { int td = (scnt[d] + 63) >> 6; if (rem < td) break; rem -= td; }
    if (d >= ND) return;
    const int cd = scnt[d];
    const int base = rem * 64;
    if (tid < 64) {
        int s = base + tid;
        nmap[tid] = (s < cd) ? rowmap[d * NNODES + s] : -1;
    }
    __syncthreads();
    const int grow = tid >> 2, gseg = tid & 3;
    {   // gather A rows with XOR swizzle on 16B granules: c ^= row&7
        int node = nmap[grow];
        if (node < 0) node = rowmap[d * NNODES];
        const char* src = reinterpret_cast<const char*>(Mb + (size_t)node * 320);
        char* dstA = reinterpret_cast<char*>(AsCt) + grow * 640;
        #pragma unroll
        for (int j = 0; j < 10; ++j) {
            int c = gseg + 4 * j;   // 0..39
            uint4 v = *reinterpret_cast<const uint4*>(src + c * 16);
            *reinterpret_cast<uint4*>(dstA + ((c ^ (grow & 7)) * 16)) = v;
        }
    }
    __syncthreads();
    const int w = tid >> 6, lane = tid & 63, gq = lane >> 4, c16 = lane & 15;
    const int swz = (c16 & 7) << 4;
    f32x4 acc[4][4];
    #pragma unroll
    for (int rt = 0; rt < 4; ++rt)
        #pragma unroll
        for (int ct = 0; ct < 4; ++ct) acc[rt][ct] = (f32x4){0.f, 0.f, 0.f, 0.f};
    #pragma unroll
    for (int ks = 0; ks < 10; ++ks) {
        s16x8 af[4], bf[4];
        #pragma unroll
        for (int rt = 0; rt < 4; ++rt)
            af[rt] = *reinterpret_cast<const s16x8*>(
                reinterpret_cast<const char*>(AsCt) + (rt * 16 + c16) * 640 +
                ((ks * 64 + gq * 16) ^ swz));
        #pragma unroll
        for (int ct = 0; ct < 4; ++ct) {
            int cb = w * 4 + ct;
            bf[ct] = *reinterpret_cast<const s16x8*>(
                &Wtf[((((size_t)d * 16 + cb) * 10 + ks) * 64 + lane) * 8]);
        }
        #pragma unroll
        for (int rt = 0; rt < 4; ++rt)
            #pragma unroll
            for (int ct = 0; ct < 4; ++ct)
                acc[rt][ct] = __builtin_amdgcn_mfma_f32_16x16x32_bf16(af[rt], bf[ct], acc[rt][ct], 0, 0, 0);
    }
    __syncthreads();   // all As reads done; AsCt becomes Ct
    #pragma unroll
    for (int rt = 0; rt < 4; ++rt)
        #pragma unroll
        for (int jj = 0; jj < 4; ++jj) {
            int row = rt * 16 + gq * 4 + jj;
            #pragma unroll
            for (int ct = 0; ct < 4; ++ct)
                AsCt[row * 256 + w * 64 + ct * 16 + c16] = f2bf(sig1(acc[rt][ct][jj]));
        }
    __syncthreads();
    {   // scatter rows to node order (512 B contiguous per row)
        const int node = nmap[grow];
        if (node >= 0) {
            const uint4* srcC = reinterpret_cast<const uint4*>(&AsCt[grow * 256]);
            uint4* dst = reinterpret_cast<uint4*>(hout + (size_t)node * 256);
            #pragma unroll
            for (int j = 0; j < 8; ++j) dst[gseg * 8 + j] = srcC[gseg * 8 + j];
        }
    }
}

// ================= D4: sparse m_h from bf16 h -> Mb cols 0..255 =================
__global__ __launch_bounds__(256) void k_mh_sparse(const float* __restrict__ g,
                                                   const unsigned short* __restrict__ hb,
                                                   unsigned short* __restrict__ Mb) {
    __shared__ __align__(16) unsigned short hs[NN * 256];   // 32 KB
    const int b = blockIdx.x;
    const int tid = threadIdx.x;
    {
        const uint4* src = reinterpret_cast<const uint4*>(hb) + (size_t)b * 2048;
        uint4* dst = reinterpret_cast<uint4*>(hs);
        #pragma unroll
        for (int j = 0; j < 8; ++j) dst[j * 256 + tid] = src[j * 256 + tid];
    }
    __syncthreads();
    const int wv = tid >> 6, lane = tid & 63;
    for (int s = 0; s < 16; ++s) {
        const int v = wv * 16 + s;
        float gval = g[((size_t)b * 64 + v) * 64 + lane];
        unsigned long long mask = __ballot(gval != 0.f);
        if (__popcll(mask) > 10) continue;
        float4 acc = make_float4(0.f, 0.f, 0.f, 0.f);
        while (mask) {
            int w = __builtin_ctzll(mask); mask &= mask - 1;
            ushort4 hv = *reinterpret_cast<const ushort4*>(&hs[w * 256 + lane * 4]);
            acc.x += bf2f(hv.x); acc.y += bf2f(hv.y);
            acc.z += bf2f(hv.z); acc.w += bf2f(hv.w);
        }
        ushort4 u = make_ushort4(f2bf(acc.x), f2bf(acc.y), f2bf(acc.z), f2bf(acc.w));
        *reinterpret_cast<ushort4*>(&Mb[((size_t)b * 64 + v) * 320 + lane * 4]) = u;
    }
}

// ================= D6: readout (3 layers, LDS-staged A + frag B) + MLP =================
__global__ __launch_bounds__(256) void k_readout_mlp(
        const unsigned short* __restrict__ hb0,
        const unsigned short* __restrict__ hb1,
        const unsigned short* __restrict__ hb2,
        const unsigned short* __restrict__ Rtf,
        const int* __restrict__ degidx,
        const float* __restrict__ fc0w, const float* __restrict__ fc0b,
        const float* __restrict__ fc1w, const float* __restrict__ fc1b,
        const float* __restrict__ fc2w, const float* __restrict__ fc2b,
        const float* __restrict__ fc3w, const float* __restrict__ fc3b,
        float* __restrict__ out) {
    const int b = blockIdx.x;
    const int tid = threadIdx.x;
    const int w = tid >> 6, lane = tid & 63, gq = lane >> 4, c16 = lane & 15;
    __shared__ __align__(16) unsigned short Ah[64 * 256];   // 32 KB swizzled
    __shared__ float x0[512];
    __shared__ float red2[4][64];
    __shared__ __align__(16) float red3[64];
    __shared__ float flags[64];
    __shared__ float part[256];
    __shared__ float x1[128], x2[256], x3[128];
    if (tid < 64) flags[tid] = (degidx[b * 64 + tid] >= 0) ? 1.f : 0.f;
    x0[tid] = 0.f; x0[tid + 256] = 0.f;
    const int swz = (c16 & 7) << 4;

    for (int layer = 0; layer < 3; ++layer) {
        const unsigned short* hb = (layer == 0) ? hb0 : ((layer == 1) ? hb1 : hb2);
        {   // stage A tile, XOR-swizzled
            const char* src = reinterpret_cast<const char*>(hb + (size_t)b * 64 * 256);
            #pragma unroll
            for (int j = 0; j < 8; ++j) {
                int l = j * 4096 + tid * 16;
                int row = l >> 9;
                int wb = l & 511;
                uint4 v = *reinterpret_cast<const uint4*>(src + l);
                *reinterpret_cast<uint4*>(
                    reinterpret_cast<char*>(Ah) + row * 512 + (wb ^ ((row & 7) << 4))) = v;
            }
        }
        __syncthreads();
        f32x4 acc[4][8];
        #pragma unroll
        for (int rt = 0; rt < 4; ++rt)
            #pragma unroll
            for (int ct = 0; ct < 8; ++ct) acc[rt][ct] = (f32x4){0.f, 0.f, 0.f, 0.f};
        #pragma unroll
        for (int ks = 0; ks < 8; ++ks) {
            s16x8 af[4], bf[8];
            #pragma unroll
            for (int rt = 0; rt < 4; ++rt)
                af[rt] = *reinterpret_cast<const s16x8*>(
                    reinterpret_cast<const char*>(Ah) + (rt * 16 + c16) * 512 +
                    ((ks * 64 + gq * 16) ^ swz));
            #pragma unroll
            for (int ct = 0; ct < 8; ++ct)
                bf[ct] = *reinterpret_cast<const s16x8*>(
                    &Rtf[((((size_t)layer * 32 + w * 8 + ct) * 8 + ks) * 64 + lane) * 8]);
            #pragma unroll
            for (int rt = 0; rt < 4; ++rt)
                #pragma unroll
                for (int ct = 0; ct < 8; ++ct)
                    acc[rt][ct] = __builtin_amdgcn_mfma_f32_16x16x32_bf16(af[rt], bf[ct], acc[rt][ct], 0, 0, 0);
        }
        // exp in place; per-row sums over this wave's 128 cols
        float rs[4][4];
        #pragma unroll
        for (int rt = 0; rt < 4; ++rt) {
            #pragma unroll
            for (int j = 0; j < 4; ++j) rs[rt][j] = 0.f;
            #pragma unroll
            for (int ct = 0; ct < 8; ++ct) {
                #pragma unroll
                for (int j = 0; j < 4; ++j) {
                    float p = __expf(acc[rt][ct][j]);
                    acc[rt][ct][j] = p;
                    rs[rt][j] += p;
                }
            }
        }
        #pragma unroll
        for (int rt = 0; rt < 4; ++rt)
            #pragma unroll
            for (int j = 0; j < 4; ++j) {
                float s = rs[rt][j];
                #pragma unroll
                for (int m = 1; m <= 8; m <<= 1) s += __shfl_xor(s, m);
                rs[rt][j] = s;
            }
        if (c16 == 0) {
            #pragma unroll
            for (int rt = 0; rt < 4; ++rt)
                #pragma unroll
                for (int j = 0; j < 4; ++j)
                    red2[w][rt * 16 + gq * 4 + j] = rs[rt][j];
        }
        __syncthreads();
        if (tid < 64) {
            float s = red2[0][tid] + red2[1][tid] + red2[2][tid] + red2[3][tid];
            red3[tid] = ((layer == 0) ? 1.f : flags[tid]) / s;
        }
        __syncthreads();
        f32x4 iv[4];
        #pragma unroll
        for (int rt = 0; rt < 4; ++rt)
            iv[rt] = *reinterpret_cast<const f32x4*>(&red3[rt * 16 + gq * 4]);
        #pragma unroll
        for (int ct = 0; ct < 8; ++ct) {
            f32x4 t = (f32x4){0.f, 0.f, 0.f, 0.f};
            #pragma unroll
            for (int rt = 0; rt < 4; ++rt) t += acc[rt][ct] * iv[rt];
            float v = t[0] + t[1] + t[2] + t[3];
            v += __shfl_xor(v, 16);
            v += __shfl_xor(v, 32);
            if (lane < 16) x0[w * 128 + ct * 16 + lane] += v;
        }
        __syncthreads();
    }
    // ---- MLP on x0[512] ----
    {
        const int o = tid & 127, half = tid >> 7;
        float a = 0.f;
        const int i0 = half * 256;
        for (int i = 0; i < 256; ++i) a = fmaf(x0[i0 + i], fc0w[(size_t)(i0 + i) * 128 + o], a);
        part[tid] = a;
    }
    __syncthreads();
    if (tid < 128) x1[tid] = fmaxf(fc0b[tid] + part[tid] + part[tid + 128], 0.f);
    __syncthreads();
    {
        float a = fc1b[tid];
        for (int i = 0; i < 128; ++i) a = fmaf(x1[i], fc1w[(size_t)i * 256 + tid], a);
        x2[tid] = fmaxf(a, 0.f);
    }
    __syncthreads();
    {
        const int o = tid & 127, half = tid >> 7;
        float a = 0.f;
        const int i0 = half * 128;
        for (int i = 0; i < 128; ++i) a = fmaf(x2[i0 + i], fc2w[(size_t)(i0 + i) * 128 + o], a);
        part[tid] = a;
    }
    __syncthreads();
    if (tid < 128) x3[tid] = fmaxf(fc2b[tid] + part[tid] + part[tid + 128], 0.f);
    __syncthreads();
    if (tid < TGT) {
        float a = fc3b[tid];
        for (int i = 0; i < 128; ++i) a = fmaf(x3[i], fc3w[(size_t)i * TGT + tid], a);
        out[(size_t)b * TGT + tid] = a;
    }
}

extern "C" void kernel_launch(void* const* d_in, const int* in_sizes, int n_in,
                              void* d_out, int out_size, void* d_ws, size_t ws_size,
                              hipStream_t stream) {
    (void)in_sizes; (void)n_in; (void)out_size; (void)ws_size;
    const float* g    = (const float*)d_in[0];
    const float* h_in = (const float*)d_in[1];
    const float* e    = (const float*)d_in[2];
    const float* Wu0  = (const float*)d_in[3];
    const float* Wu1  = (const float*)d_in[4];
    const float* R    = (const float*)d_in[5];
    const float* fc0w = (const float*)d_in[6];
    const float* fc0b = (const float*)d_in[7];
    const float* fc1w = (const float*)d_in[8];
    const float* fc1b = (const float*)d_in[9];
    const float* fc2w = (const float*)d_in[10];
    const float* fc2b = (const float*)d_in[11];
    const float* fc3w = (const float*)d_in[12];
    const float* fc3b = (const float*)d_in[13];
    float* out = (float*)d_out;

    char* p = (char*)d_ws;
    unsigned short* Mb   = (unsigned short*)p; p += (size_t)NNODES * 320 * 2;       // 10 MB
    unsigned short* hb0  = (unsigned short*)p; p += (size_t)NNODES * 256 * 2;       // 8 MB
    unsigned short* hb1  = (unsigned short*)p; p += (size_t)NNODES * 256 * 2;       // 8 MB
    unsigned short* hb2  = (unsigned short*)p; p += (size_t)NNODES * 256 * 2;       // 8 MB
    unsigned short* Rtf  = (unsigned short*)p; p += (size_t)3 * 32 * 8 * 512 * 2;   // 0.75 MB
    unsigned short* Wtf0 = (unsigned short*)p; p += (size_t)ND * 16 * 10 * 512 * 2; // 1.76 MB
    unsigned short* Wtf1 = (unsigned short*)p; p += (size_t)ND * 16 * 10 * 512 * 2; // 1.76 MB
    int* degidx = (int*)p;                     p += (size_t)NNODES * 4;             // 64 KB
    int* rowmap = (int*)p;                     p += (size_t)ND * NNODES * 4;        // 704 KB
    int* cnt    = (int*)p;                     p += 1024;

    hipMemsetAsync(cnt, 0, ND * sizeof(int), stream);
    k_prep_light<<<NB_LIGHT, 256, 0, stream>>>(g, e, R, Wu0, Wu1,
                                               Mb, Rtf, Wtf0, Wtf1,
                                               degidx, rowmap, cnt, hb1, hb2);
    k_prep_mh<<<BB, 256, 0, stream>>>(g, h_in, Mb, hb0);
    k_update<<<NNODES / 64 + ND, 256, 0, stream>>>(Mb, Wtf0, rowmap, cnt, hb1);
    k_mh_sparse<<<BB, 256, 0, stream>>>(g, hb1, Mb);
    k_update<<<NNODES / 64 + ND, 256, 0, stream>>>(Mb, Wtf1, rowmap, cnt, hb2);
    k_readout_mlp<<<BB, 256, 0, stream>>>(hb0, hb1, hb2, Rtf, degidx,
                                          fc0w, fc0b, fc1w, fc1b, fc2w, fc2b, fc3w, fc3b, out);
}

// Round 17
// 123.362 us; speedup vs baseline: 1.0571x; 1.0312x over previous
//
#include <hip/hip_runtime.h>
#include <hip/hip_bf16.h>

#define BB 256
#define NN 64
#define NNODES 16384   // BB*NN
#define ND 11
#define TGT 12
#define NTILE (NNODES / 64 + ND)   // static upper bound on 64-row tiles

// k_prep_light role bases (no-LDS roles)
#define NB_DEG   64
#define NB_MEDEG 4096
#define NB_CVTR  96
#define NB_CVTW  352
#define NB_LIGHT (NB_DEG + NB_MEDEG + NB_CVTR + NB_CVTW)

typedef __attribute__((ext_vector_type(8))) short s16x8;
typedef __attribute__((ext_vector_type(4))) float f32x4;

__device__ __forceinline__ float sig1(float v) { return 1.f / (1.f + __expf(-v)); }
__device__ __forceinline__ float bf2f(unsigned short u) {
    union { unsigned int i; float f; } v; v.i = ((unsigned int)u) << 16; return v.f;
}
__device__ __forceinline__ unsigned short f2bf(float f) {
    __hip_bfloat16 b = __float2bfloat16(f);   // RNE
    return *reinterpret_cast<unsigned short*>(&b);
}

// ================= D1a: light prep (88 B LDS -> high occupancy) =================
// roles: [deg | me_deg(SPARSE) | cvt_R | cvt_W(0+1)]
__global__ __launch_bounds__(256) void k_prep_light(
        const float* __restrict__ g, const float* __restrict__ e,
        const float* __restrict__ R,
        const float* __restrict__ Wu0, const float* __restrict__ Wu1,
        unsigned short* __restrict__ Mb,
        unsigned short* __restrict__ Rtf, unsigned short* __restrict__ Wtf0,
        unsigned short* __restrict__ Wtf1, int* __restrict__ degidx,
        int* __restrict__ rowmap, int* __restrict__ cnt,
        unsigned short* __restrict__ hb1, unsigned short* __restrict__ hb2) {
    __shared__ int hist[ND];
    __shared__ int baseg[ND];
    int bid = blockIdx.x;
    const int tid = threadIdx.x;
    const int lane = tid & 63, wv = tid >> 6;
    const int gq = lane >> 4, c16 = lane & 15;

    if (bid < NB_DEG) {
        // ---- deg: degree + bucket rank (hierarchical), rowmap scatter, zero invalid rows ----
        if (tid < ND) hist[tid] = 0;
        __syncthreads();
        const int node = bid * 256 + tid;
        const float4* gr = reinterpret_cast<const float4*>(g + (size_t)node * 64);
        float s = 0.f;
        #pragma unroll
        for (int j = 0; j < 16; ++j) { float4 v = gr[j]; s += v.x + v.y + v.z + v.w; }
        const int di = (int)(s + 0.5f);
        const bool valid = di < ND;
        int pl = 0;
        if (valid) pl = atomicAdd(&hist[di], 1);
        __syncthreads();
        if (tid < ND) baseg[tid] = hist[tid] ? atomicAdd(&cnt[tid], hist[tid]) : 0;
        __syncthreads();
        degidx[node] = valid ? di : -1;
        if (valid) {
            rowmap[di * NNODES + baseg[di] + pl] = node;
        } else {
            uint4 z = make_uint4(0, 0, 0, 0);
            uint4* p1 = reinterpret_cast<uint4*>(hb1 + (size_t)node * 256);
            uint4* p2 = reinterpret_cast<uint4*>(hb2 + (size_t)node * 256);
            #pragma unroll
            for (int k = 0; k < 32; ++k) { p1[k] = z; p2[k] = z; }
        }
        return;
    }
    bid -= NB_DEG;

    if (bid < NB_MEDEG) {
        // ---- me_deg SPARSE: m_e = sum of e-rows over set neighbors only (~5/64) ----
        const int node = bid * 4 + wv;
        const float gv = g[(size_t)node * 64 + lane];
        unsigned long long mask = __ballot(gv != 0.f);
        if (__popcll(mask) > 10) return;   // invalid: m_e never consumed
        const float* eb = e + (size_t)node * 4096;
        float acc = 0.f;
        while (mask) {
            int w = __builtin_ctzll(mask); mask &= mask - 1;
            acc += eb[w * 64 + lane];      // 256 B coalesced per neighbor
        }
        Mb[(size_t)node * 320 + 256 + lane] = f2bf(acc);
        return;
    }
    bid -= NB_MEDEG;

    if (bid < NB_CVTR) {
        // ---- cvt_R -> fragment order ----
        const int l = bid >> 5, cb = bid & 31;
        const float* Rl = R + (size_t)l * 256 * 512;
        unsigned short* outB = Rtf + ((size_t)l * 32 + cb) * 8 * 512;
        const int col = cb * 16 + c16;
        #pragma unroll
        for (int it = 0; it < 2; ++it) {
            int ks = wv + it * 4;
            unsigned short tmp[8];
            #pragma unroll
            for (int j = 0; j < 8; ++j)
                tmp[j] = f2bf(Rl[(size_t)(ks * 32 + gq * 8 + j) * 512 + col]);
            *reinterpret_cast<uint4*>(&outB[(size_t)ks * 512 + lane * 8]) =
                *reinterpret_cast<const uint4*>(tmp);
        }
        return;
    }
    bid -= NB_CVTR;

    {   // ---- cvt_W -> fragment order ----
        const int wsel = bid / 176, rem = bid % 176;
        const int d = rem >> 4, cb = rem & 15;
        const float* Wd = (wsel ? Wu1 : Wu0) + (size_t)d * 320 * 256;
        unsigned short* outB = (wsel ? Wtf1 : Wtf0) + ((size_t)d * 16 + cb) * 10 * 512;
        const int col = cb * 16 + c16;
        #pragma unroll
        for (int it = 0; it < 3; ++it) {
            int ks = wv + it * 4;
            if (ks < 10) {
                unsigned short tmp[8];
                #pragma unroll
                for (int j = 0; j < 8; ++j)
                    tmp[j] = f2bf(Wd[(size_t)(ks * 32 + gq * 8 + j) * 256 + col]);
                *reinterpret_cast<uint4*>(&outB[(size_t)ks * 512 + lane * 8]) =
                    *reinterpret_cast<const uint4*>(tmp);
            }
        }
    }
}

// ================= D1b: mh0 + cvt_h (32 KB LDS, 256 blocks) =================
__global__ __launch_bounds__(256) void k_prep_mh(
        const float* __restrict__ g, const float* __restrict__ h_in,
        unsigned short* __restrict__ Mb, unsigned short* __restrict__ hb0) {
    __shared__ __align__(16) unsigned short hs[NN * 256];   // 32 KB
    const int b = blockIdx.x;
    const int tid = threadIdx.x;
    const int lane = tid & 63, wv = tid >> 6;
    const float4* hin4 = reinterpret_cast<const float4*>(h_in) + (size_t)b * 4096;
    ushort4* hb0b = reinterpret_cast<ushort4*>(hb0 + (size_t)b * NN * 256);
    #pragma unroll
    for (int j = 0; j < 16; ++j) {
        int i = j * 256 + tid;
        float4 v = hin4[i];
        ushort4 u = make_ushort4(f2bf(v.x), f2bf(v.y), f2bf(v.z), f2bf(v.w));
        *reinterpret_cast<ushort4*>(&hs[i * 4]) = u;
        hb0b[i] = u;   // cvt_h fused: one h_in pass
    }
    __syncthreads();
    for (int s = 0; s < 16; ++s) {
        const int v = wv * 16 + s;
        float gval = g[((size_t)b * 64 + v) * 64 + lane];
        unsigned long long mask = __ballot(gval != 0.f);
        if (__popcll(mask) > 10) continue;
        float4 acc = make_float4(0.f, 0.f, 0.f, 0.f);
        while (mask) {
            int w = __builtin_ctzll(mask); mask &= mask - 1;
            ushort4 hv = *reinterpret_cast<const ushort4*>(&hs[w * 256 + lane * 4]);
            acc.x += bf2f(hv.x); acc.y += bf2f(hv.y);
            acc.z += bf2f(hv.z); acc.w += bf2f(hv.w);
        }
        ushort4 u = make_ushort4(f2bf(acc.x), f2bf(acc.y), f2bf(acc.z), f2bf(acc.w));
        *reinterpret_cast<ushort4*>(&Mb[((size_t)b * 64 + v) * 320 + lane * 4]) = u;
    }
}

// ================= D3/D5: grouped update; single-degree tiles, col-split x2 =================
// Block = (tile, col-half): 64 rows x 128 cols -> 2 blocks/CU for latency hiding.
__global__ __launch_bounds__(256) void k_update(
        const unsigned short* __restrict__ Mb,
        const unsigned short* __restrict__ Wtf,
        const int* __restrict__ rowmap,
        const int* __restrict__ cnt,
        unsigned short* __restrict__ hout) {
    __shared__ __align__(16) unsigned short AsCt[64 * 320];   // 40 KB (As; Ct aliases low 16 KB)
    __shared__ int nmap[64];
    __shared__ int scnt[ND];
    const int tid = threadIdx.x;
    if (tid < ND) scnt[tid] = cnt[tid];
    __syncthreads();
    const int half = blockIdx.x & 1;
    int rem = blockIdx.x >> 1, d = 0;
    for (; d < ND; ++d) { int td = (scnt[d] + 63) >> 6; if (rem < td) break; rem -= td; }
    if (d >= ND) return;
    const int cd = scnt[d];
    const int base = rem * 64;
    if (tid < 64) {
        int s = base + tid;
        nmap[tid] = (s < cd) ? rowmap[d * NNODES + s] : -1;
    }
    __syncthreads();
    const int grow = tid >> 2, gseg = tid & 3;
    {   // gather A rows with XOR swizzle on 16B granules: c ^= row&7
        int node = nmap[grow];
        if (node < 0) node = rowmap[d * NNODES];
        const char* src = reinterpret_cast<const char*>(Mb + (size_t)node * 320);
        char* dstA = reinterpret_cast<char*>(AsCt) + grow * 640;
        #pragma unroll
        for (int j = 0; j < 10; ++j) {
            int c = gseg + 4 * j;   // 0..39
            uint4 v = *reinterpret_cast<const uint4*>(src + c * 16);
            *reinterpret_cast<uint4*>(dstA + ((c ^ (grow & 7)) * 16)) = v;
        }
    }
    __syncthreads();
    const int w = tid >> 6, lane = tid & 63, gq = lane >> 4, c16 = lane & 15;
    const int swz = (c16 & 7) << 4;
    const int cb0 = half * 8 + w * 2;   // this wave's two 16-col blocks
    f32x4 acc[4][2];
    #pragma unroll
    for (int rt = 0; rt < 4; ++rt) {
        acc[rt][0] = (f32x4){0.f, 0.f, 0.f, 0.f};
        acc[rt][1] = (f32x4){0.f, 0.f, 0.f, 0.f};
    }
    #pragma unroll
    for (int ks = 0; ks < 10; ++ks) {
        s16x8 af[4], bf[2];
        #pragma unroll
        for (int rt = 0; rt < 4; ++rt)
            af[rt] = *reinterpret_cast<const s16x8*>(
                reinterpret_cast<const char*>(AsCt) + (rt * 16 + c16) * 640 +
                ((ks * 64 + gq * 16) ^ swz));
        #pragma unroll
        for (int ct = 0; ct < 2; ++ct)
            bf[ct] = *reinterpret_cast<const s16x8*>(
                &Wtf[((((size_t)d * 16 + cb0 + ct) * 10 + ks) * 64 + lane) * 8]);
        #pragma unroll
        for (int rt = 0; rt < 4; ++rt) {
            acc[rt][0] = __builtin_amdgcn_mfma_f32_16x16x32_bf16(af[rt], bf[0], acc[rt][0], 0, 0, 0);
            acc[rt][1] = __builtin_amdgcn_mfma_f32_16x16x32_bf16(af[rt], bf[1], acc[rt][1], 0, 0, 0);
        }
    }
    __syncthreads();   // all As reads done; low 16 KB of AsCt becomes Ct[64][128]
    #pragma unroll
    for (int rt = 0; rt < 4; ++rt)
        #pragma unroll
        for (int jj = 0; jj < 4; ++jj) {
            int row = rt * 16 + gq * 4 + jj;
            AsCt[row * 128 + w * 32 + c16]      = f2bf(sig1(acc[rt][0][jj]));
            AsCt[row * 128 + w * 32 + 16 + c16] = f2bf(sig1(acc[rt][1][jj]));
        }
    __syncthreads();
    {   // scatter rows to node order (256 B contiguous per row-half)
        const int node = nmap[grow];
        if (node >= 0) {
            const uint4* srcC = reinterpret_cast<const uint4*>(&AsCt[grow * 128]);
            uint4* dst = reinterpret_cast<uint4*>(hout + (size_t)node * 256 + half * 128);
            #pragma unroll
            for (int j = 0; j < 4; ++j) dst[gseg * 4 + j] = srcC[gseg * 4 + j];
        }
    }
}

// ================= D4: sparse m_h from bf16 h -> Mb cols 0..255 =================
__global__ __launch_bounds__(256) void k_mh_sparse(const float* __restrict__ g,
                                                   const unsigned short* __restrict__ hb,
                                                   unsigned short* __restrict__ Mb) {
    __shared__ __align__(16) unsigned short hs[NN * 256];   // 32 KB
    const int b = blockIdx.x;
    const int tid = threadIdx.x;
    {
        const uint4* src = reinterpret_cast<const uint4*>(hb) + (size_t)b * 2048;
        uint4* dst = reinterpret_cast<uint4*>(hs);
        #pragma unroll
        for (int j = 0; j < 8; ++j) dst[j * 256 + tid] = src[j * 256 + tid];
    }
    __syncthreads();
    const int wv = tid >> 6, lane = tid & 63;
    for (int s = 0; s < 16; ++s) {
        const int v = wv * 16 + s;
        float gval = g[((size_t)b * 64 + v) * 64 + lane];
        unsigned long long mask = __ballot(gval != 0.f);
        if (__popcll(mask) > 10) continue;
        float4 acc = make_float4(0.f, 0.f, 0.f, 0.f);
        while (mask) {
            int w = __builtin_ctzll(mask); mask &= mask - 1;
            ushort4 hv = *reinterpret_cast<const ushort4*>(&hs[w * 256 + lane * 4]);
            acc.x += bf2f(hv.x); acc.y += bf2f(hv.y);
            acc.z += bf2f(hv.z); acc.w += bf2f(hv.w);
        }
        ushort4 u = make_ushort4(f2bf(acc.x), f2bf(acc.y), f2bf(acc.z), f2bf(acc.w));
        *reinterpret_cast<ushort4*>(&Mb[((size_t)b * 64 + v) * 320 + lane * 4]) = u;
    }
}

// ================= D6: readout (3 layers, LDS-staged A + frag B) + MLP =================
__global__ __launch_bounds__(256) void k_readout_mlp(
        const unsigned short* __restrict__ hb0,
        const unsigned short* __restrict__ hb1,
        const unsigned short* __restrict__ hb2,
        const unsigned short* __restrict__ Rtf,
        const int* __restrict__ degidx,
        const float* __restrict__ fc0w, const float* __restrict__ fc0b,
        const float* __restrict__ fc1w, const float* __restrict__ fc1b,
        const float* __restrict__ fc2w, const float* __restrict__ fc2b,
        const float* __restrict__ fc3w, const float* __restrict__ fc3b,
        float* __restrict__ out) {
    const int b = blockIdx.x;
    const int tid = threadIdx.x;
    const int w = tid >> 6, lane = tid & 63, gq = lane >> 4, c16 = lane & 15;
    __shared__ __align__(16) unsigned short Ah[64 * 256];   // 32 KB swizzled
    __shared__ float x0[512];
    __shared__ float red2[4][64];
    __shared__ __align__(16) float red3[64];
    __shared__ float flags[64];
    __shared__ float part[256];
    __shared__ float x1[128], x2[256], x3[128];
    if (tid < 64) flags[tid] = (degidx[b * 64 + tid] >= 0) ? 1.f : 0.f;
    x0[tid] = 0.f; x0[tid + 256] = 0.f;
    const int swz = (c16 & 7) << 4;

    for (int layer = 0; layer < 3; ++layer) {
        const unsigned short* hb = (layer == 0) ? hb0 : ((layer == 1) ? hb1 : hb2);
        {   // stage A tile, XOR-swizzled
            const char* src = reinterpret_cast<const char*>(hb + (size_t)b * 64 * 256);
            #pragma unroll
            for (int j = 0; j < 8; ++j) {
                int l = j * 4096 + tid * 16;
                int row = l >> 9;
                int wb = l & 511;
                uint4 v = *reinterpret_cast<const uint4*>(src + l);
                *reinterpret_cast<uint4*>(
                    reinterpret_cast<char*>(Ah) + row * 512 + (wb ^ ((row & 7) << 4))) = v;
            }
        }
        __syncthreads();
        f32x4 acc[4][8];
        #pragma unroll
        for (int rt = 0; rt < 4; ++rt)
            #pragma unroll
            for (int ct = 0; ct < 8; ++ct) acc[rt][ct] = (f32x4){0.f, 0.f, 0.f, 0.f};
        #pragma unroll
        for (int ks = 0; ks < 8; ++ks) {
            s16x8 af[4], bf[8];
            #pragma unroll
            for (int rt = 0; rt < 4; ++rt)
                af[rt] = *reinterpret_cast<const s16x8*>(
                    reinterpret_cast<const char*>(Ah) + (rt * 16 + c16) * 512 +
                    ((ks * 64 + gq * 16) ^ swz));
            #pragma unroll
            for (int ct = 0; ct < 8; ++ct)
                bf[ct] = *reinterpret_cast<const s16x8*>(
                    &Rtf[((((size_t)layer * 32 + w * 8 + ct) * 8 + ks) * 64 + lane) * 8]);
            #pragma unroll
            for (int rt = 0; rt < 4; ++rt)
                #pragma unroll
                for (int ct = 0; ct < 8; ++ct)
                    acc[rt][ct] = __builtin_amdgcn_mfma_f32_16x16x32_bf16(af[rt], bf[ct], acc[rt][ct], 0, 0, 0);
        }
        // exp in place; per-row sums over this wave's 128 cols
        float rs[4][4];
        #pragma unroll
        for (int rt = 0; rt < 4; ++rt) {
            #pragma unroll
            for (int j = 0; j < 4; ++j) rs[rt][j] = 0.f;
            #pragma unroll
            for (int ct = 0; ct < 8; ++ct) {
                #pragma unroll
                for (int j = 0; j < 4; ++j) {
                    float p = __expf(acc[rt][ct][j]);
                    acc[rt][ct][j] = p;
                    rs[rt][j] += p;
                }
            }
        }
        #pragma unroll
        for (int rt = 0; rt < 4; ++rt)
            #pragma unroll
            for (int j = 0; j < 4; ++j) {
                float s = rs[rt][j];
                #pragma unroll
                for (int m = 1; m <= 8; m <<= 1) s += __shfl_xor(s, m);
                rs[rt][j] = s;
            }
        if (c16 == 0) {
            #pragma unroll
            for (int rt = 0; rt < 4; ++rt)
                #pragma unroll
                for (int j = 0; j < 4; ++j)
                    red2[w][rt * 16 + gq * 4 + j] = rs[rt][j];
        }
        __syncthreads();
        if (tid < 64) {
            float s = red2[0][tid] + red2[1][tid] + red2[2][tid] + red2[3][tid];
            red3[tid] = ((layer == 0) ? 1.f : flags[tid]) / s;
        }
        __syncthreads();
        f32x4 iv[4];
        #pragma unroll
        for (int rt = 0; rt < 4; ++rt)
            iv[rt] = *reinterpret_cast<const f32x4*>(&red3[rt * 16 + gq * 4]);
        #pragma unroll
        for (int ct = 0; ct < 8; ++ct) {
            f32x4 t = (f32x4){0.f, 0.f, 0.f, 0.f};
            #pragma unroll
            for (int rt = 0; rt < 4; ++rt) t += acc[rt][ct] * iv[rt];
            float v = t[0] + t[1] + t[2] + t[3];
            v += __shfl_xor(v, 16);
            v += __shfl_xor(v, 32);
            if (lane < 16) x0[w * 128 + ct * 16 + lane] += v;
        }
        __syncthreads();
    }
    // ---- MLP on x0[512] ----
    {
        const int o = tid & 127, half = tid >> 7;
        float a = 0.f;
        const int i0 = half * 256;
        for (int i = 0; i < 256; ++i) a = fmaf(x0[i0 + i], fc0w[(size_t)(i0 + i) * 128 + o], a);
        part[tid] = a;
    }
    __syncthreads();
    if (tid < 128) x1[tid] = fmaxf(fc0b[tid] + part[tid] + part[tid + 128], 0.f);
    __syncthreads();
    {
        float a = fc1b[tid];
        for (int i = 0; i < 128; ++i) a = fmaf(x1[i], fc1w[(size_t)i * 256 + tid], a);
        x2[tid] = fmaxf(a, 0.f);
    }
    __syncthreads();
    {
        const int o = tid & 127, half = tid >> 7;
        float a = 0.f;
        const int i0 = half * 128;
        for (int i = 0; i < 128; ++i) a = fmaf(x2[i0 + i], fc2w[(size_t)(i0 + i) * 128 + o], a);
        part[tid] = a;
    }
    __syncthreads();
    if (tid < 128) x3[tid] = fmaxf(fc2b[tid] + part[tid] + part[tid + 128], 0.f);
    __syncthreads();
    if (tid < TGT) {
        float a = fc3b[tid];
        for (int i = 0; i < 128; ++i) a = fmaf(x3[i], fc3w[(size_t)i * TGT + tid], a);
        out[(size_t)b * TGT + tid] = a;
    }
}

extern "C" void kernel_launch(void* const* d_in, const int* in_sizes, int n_in,
                              void* d_out, int out_size, void* d_ws, size_t ws_size,
                              hipStream_t stream) {
    (void)in_sizes; (void)n_in; (void)out_size; (void)ws_size;
    const float* g    = (const float*)d_in[0];
    const float* h_in = (const float*)d_in[1];
    const float* e    = (const float*)d_in[2];
    const float* Wu0  = (const float*)d_in[3];
    const float* Wu1  = (const float*)d_in[4];
    const float* R    = (const float*)d_in[5];
    const float* fc0w = (const float*)d_in[6];
    const float* fc0b = (const float*)d_in[7];
    const float* fc1w = (const float*)d_in[8];
    const float* fc1b = (const float*)d_in[9];
    const float* fc2w = (const float*)d_in[10];
    const float* fc2b = (const float*)d_in[11];
    const float* fc3w = (const float*)d_in[12];
    const float* fc3b = (const float*)d_in[13];
    float* out = (float*)d_out;

    char* p = (char*)d_ws;
    unsigned short* Mb   = (unsigned short*)p; p += (size_t)NNODES * 320 * 2;       // 10 MB
    unsigned short* hb0  = (unsigned short*)p; p += (size_t)NNODES * 256 * 2;       // 8 MB
    unsigned short* hb1  = (unsigned short*)p; p += (size_t)NNODES * 256 * 2;       // 8 MB
    unsigned short* hb2  = (unsigned short*)p; p += (size_t)NNODES * 256 * 2;       // 8 MB
    unsigned short* Rtf  = (unsigned short*)p; p += (size_t)3 * 32 * 8 * 512 * 2;   // 0.75 MB
    unsigned short* Wtf0 = (unsigned short*)p; p += (size_t)ND * 16 * 10 * 512 * 2; // 1.76 MB
    unsigned short* Wtf1 = (unsigned short*)p; p += (size_t)ND * 16 * 10 * 512 * 2; // 1.76 MB
    int* degidx = (int*)p;                     p += (size_t)NNODES * 4;             // 64 KB
    int* rowmap = (int*)p;                     p += (size_t)ND * NNODES * 4;        // 704 KB
    int* cnt    = (int*)p;                     p += 1024;

    hipMemsetAsync(cnt, 0, ND * sizeof(int), stream);
    k_prep_light<<<NB_LIGHT, 256, 0, stream>>>(g, e, R, Wu0, Wu1,
                                               Mb, Rtf, Wtf0, Wtf1,
                                               degidx, rowmap, cnt, hb1, hb2);
    k_prep_mh<<<BB, 256, 0, stream>>>(g, h_in, Mb, hb0);
    k_update<<<2 * NTILE, 256, 0, stream>>>(Mb, Wtf0, rowmap, cnt, hb1);
    k_mh_sparse<<<BB, 256, 0, stream>>>(g, hb1, Mb);
    k_update<<<2 * NTILE, 256, 0, stream>>>(Mb, Wtf1, rowmap, cnt, hb2);
    k_readout_mlp<<<BB, 256, 0, stream>>>(hb0, hb1, hb2, Rtf, degidx,
                                          fc0w, fc0b, fc1w, fc1b, fc2w, fc2b, fc3w, fc3b, out);
}